// Round 7
// baseline (540.238 us; speedup 1.0000x reference)
//
#include <hip/hip_runtime.h>
#include <stdint.h>
#include <stddef.h>

#define BATCH  16
#define HEADS  8
#define NTOK   4096      // H*W
#define CDIM   512
#define FDIM   1536      // 3*C

typedef short bf16x8 __attribute__((ext_vector_type(8)));
typedef float fx4    __attribute__((ext_vector_type(4)));

__device__ __forceinline__ uint16_t f2bf(float f) {
    uint32_t u = __float_as_uint(f);
    return (uint16_t)((u + 0x7FFFu + ((u >> 16) & 1u)) >> 16); // RNE
}
__device__ __forceinline__ float bf2f(uint16_t u) {
    return __uint_as_float(((uint32_t)u) << 16);
}
// async global->LDS, 16B per lane. LDS dest must be wave-uniform base + lane*16.
__device__ __forceinline__ void gload16(const uint16_t* g, uint16_t* l) {
    __builtin_amdgcn_global_load_lds(
        (const __attribute__((address_space(1))) uint32_t*)(g),
        (__attribute__((address_space(3))) uint32_t*)(l), 16, 0, 0);
}

// ---------------------------------------------------------------------------
// transpose_w: Wt[f][c] = bf16(qkv_w[c][f]); Pt[f][c] = bf16(proj_w[c][f])
// ---------------------------------------------------------------------------
__global__ void transpose_w_kernel(const float* __restrict__ qkv_w,
                                   const float* __restrict__ proj_w,
                                   uint16_t* __restrict__ Wt,
                                   uint16_t* __restrict__ Pt) {
    __shared__ uint16_t tile[32][33];
    int blk = blockIdx.x;
    const float* src; uint16_t* dst; int W, Hh, r0, c0;
    if (blk < 768) {                    // qkv_w: 512 x 1536
        int tr = blk / 48, tc = blk % 48;
        src = qkv_w; dst = Wt; W = 1536; Hh = 512; r0 = tr * 32; c0 = tc * 32;
    } else {                            // proj_w: 512 x 512
        blk -= 768;
        int tr = blk / 16, tc = blk % 16;
        src = proj_w; dst = Pt; W = 512; Hh = 512; r0 = tr * 32; c0 = tc * 32;
    }
    const int tx = threadIdx.x & 31, ty = threadIdx.x >> 5;   // 32 x 8
    #pragma unroll
    for (int j = 0; j < 4; j++)
        tile[ty + 8 * j][tx] = f2bf(src[(size_t)(r0 + ty + 8 * j) * W + c0 + tx]);
    __syncthreads();
    #pragma unroll
    for (int j = 0; j < 4; j++)
        dst[(size_t)(c0 + ty + 8 * j) * Hh + r0 + tx] = tile[tx][ty + 8 * j];
}

// ---------------------------------------------------------------------------
// prep: Xb = bf16(x); zero Sq/Sk (16384 contiguous floats at Sq)
// ---------------------------------------------------------------------------
__global__ void prep_kernel(const float* __restrict__ X,
                            uint16_t* __restrict__ Xb,
                            float* __restrict__ Sqk) {
    const int tid = blockIdx.x * blockDim.x + threadIdx.x;
    const int stride = gridDim.x * blockDim.x;
    for (int i = tid; i < (1 << 22); i += stride) {
        const fx4* src = reinterpret_cast<const fx4*>(X + (size_t)i * 8);
        fx4 v0 = src[0], v1 = src[1];
        union { bf16x8 v; uint16_t u[8]; } pk;
        #pragma unroll
        for (int e = 0; e < 4; e++) { pk.u[e] = f2bf(v0[e]); pk.u[4 + e] = f2bf(v1[e]); }
        reinterpret_cast<bf16x8*>(Xb)[i] = pk.v;
    }
    for (int i = tid; i < 16384; i += stride) Sqk[i] = 0.0f;
}

// ===========================================================================
// 8-phase 256x256 GEMM core (plain-HIP port of the m201 schedule).
// 8 waves (wm=w>>2, wn=w&3); wave tile 128x64 with SPLIT m-halves:
//   C row = mh*128 + wm*64 + mi*16 + lg*4 + r ; col = nh*128 + wn*32 + ni*16 + l15
// Phase (mh,nh) reads exactly A-half mh + B-half nh -> halves die progressively.
// Stage schedule (iter computes kt,kt+1): P1:(kt+1)B1 P2:(kt+1)A1 P3:(kt+2)A0
//   P4:(kt+2)B0 P5:(kt+2)B1 P6:(kt+2)A1 P7:(kt+3)A0 P8:(kt+3)B0
// Uniform vmcnt(8) per phase: outstanding 10 -> 8; retires the half first read
// 4 phases later. Every half staged >=5 phases before first read.
// Barriers are __builtin_amdgcn_s_barrier (convergent) — NOT raw asm.
// ===========================================================================
#define QPHASE(BUF, MH, NH, STAGE) do {                                        \
    bf16x8 afr[4][2], bfr2[2][2];                                              \
    _Pragma("unroll") for (int mi = 0; mi < 4; ++mi)                           \
      _Pragma("unroll") for (int ks = 0; ks < 2; ++ks) {                       \
        const int ra = wm * 64 + mi * 16 + l15;                                \
        const int ch = ks * 4 + lg;                                            \
        afr[mi][ks] = *reinterpret_cast<const bf16x8*>(                        \
            &Ab[BUF][MH][ra * 64 + ((ch ^ (ra & 7)) << 3)]);                   \
      }                                                                        \
    _Pragma("unroll") for (int ni = 0; ni < 2; ++ni)                           \
      _Pragma("unroll") for (int ks = 0; ks < 2; ++ks) {                       \
        const int rb = wn * 32 + ni * 16 + l15;                                \
        const int ch = ks * 4 + lg;                                            \
        bfr2[ni][ks] = *reinterpret_cast<const bf16x8*>(                       \
            &Bb[BUF][NH][rb * 64 + ((ch ^ (rb & 7)) << 3)]);                   \
      }                                                                        \
    STAGE;                                                                     \
    asm volatile("s_waitcnt vmcnt(8)" ::: "memory");                           \
    __builtin_amdgcn_s_barrier();                                              \
    __builtin_amdgcn_s_setprio(1);                                             \
    _Pragma("unroll") for (int mi = 0; mi < 4; ++mi)                           \
      _Pragma("unroll") for (int ni = 0; ni < 2; ++ni)                         \
        _Pragma("unroll") for (int ks = 0; ks < 2; ++ks)                       \
          acc[MH][mi][NH][ni] = __builtin_amdgcn_mfma_f32_16x16x32_bf16(       \
              afr[mi][ks], bfr2[ni][ks], acc[MH][mi][NH][ni], 0, 0, 0);        \
    __builtin_amdgcn_s_setprio(0);                                             \
    __builtin_amdgcn_s_barrier();                                              \
  } while (0)

// ---------------------------------------------------------------------------
// qkv GEMM (8-phase 256^2) + layout-split epilogue + fused sumsq.
// ---------------------------------------------------------------------------
__global__ __launch_bounds__(512, 2) void gemm_qkv_kernel(
        const uint16_t* __restrict__ Xb, const uint16_t* __restrict__ Wt,
        const float* __restrict__ q_bias, const float* __restrict__ v_bias,
        uint16_t* __restrict__ QT, uint16_t* __restrict__ KT,
        uint16_t* __restrict__ VT,
        float* __restrict__ Sq, float* __restrict__ Sk) {
    __shared__ uint16_t Ab[2][2][8192];   // [dbuf][half][128 rows x 64 k]
    __shared__ uint16_t Bb[2][2][8192];
    const int bx = blockIdx.x;
    const int swz = (bx & 7) * 192 + (bx >> 3);   // nwg=1536, bijective XCD swizzle
    const int tm = swz / 6, tn = swz % 6;
    const int gm = tm * 256, gn = tn * 256;
    const int b = gm >> 12;
    const int t = threadIdx.x, lane = t & 63, w = t >> 6;
    const int wm = w >> 2, wn = w & 3;
    const int l15 = lane & 15, lg = (lane >> 4) & 3;
    fx4 acc[2][4][2][2] = {};
    // staging geometry: thread t covers rows {t>>3, 64+(t>>3)} of a half-tile
    const int rowA = t >> 3;
    const int swA = ((t & 7) ^ (rowA & 7)) << 3;    // pre-swizzled k offset
    const uint16_t* gAb = Xb + (size_t)(gm + rowA) * 512 + swA;
    const uint16_t* gBb = Wt + (size_t)(gn + rowA) * 512 + swA;
    auto stA = [&](int kt_, int half) {
        const int bufi = kt_ & 1; const int kc = (kt_ & 7) * 64;
        gload16(gAb + (size_t)(half * 128) * 512 + kc,       &Ab[bufi][half][t * 8]);
        gload16(gAb + (size_t)(half * 128 + 64) * 512 + kc,  &Ab[bufi][half][4096 + t * 8]);
    };
    auto stB = [&](int kt_, int half) {
        const int bufi = kt_ & 1; const int kc = (kt_ & 7) * 64;
        gload16(gBb + (size_t)(half * 128) * 512 + kc,       &Bb[bufi][half][t * 8]);
        gload16(gBb + (size_t)(half * 128 + 64) * 512 + kc,  &Bb[bufi][half][4096 + t * 8]);
    };
    // prologue: kt0.A0,B0,B1,A1, kt1.A0,B0 (12 loads); retire A0,B0 of kt0
    stA(0, 0); stB(0, 0); stB(0, 1); stA(0, 1); stA(1, 0); stB(1, 0);
    asm volatile("s_waitcnt vmcnt(8)" ::: "memory");
    __builtin_amdgcn_s_barrier();
    #pragma unroll
    for (int i = 0; i < 4; ++i) {
        const int kt = 2 * i;
        QPHASE(0, 0, 0, stB(kt + 1, 1));
        QPHASE(0, 0, 1, stA(kt + 1, 1));
        QPHASE(0, 1, 0, stA(kt + 2, 0));
        QPHASE(0, 1, 1, stB(kt + 2, 0));
        QPHASE(1, 0, 0, stB(kt + 2, 1));
        QPHASE(1, 0, 1, stA(kt + 2, 1));
        QPHASE(1, 1, 0, stA(kt + 3, 0));
        QPHASE(1, 1, 1, stB(kt + 3, 0));
    }
    asm volatile("s_waitcnt vmcnt(0)" ::: "memory");
    __syncthreads();
    // ---- epilogue ----
    // chunk map: 4x 64-col chunks in this 256-col tile; u = tn*4+c; type=u%3
    int slotOf0 = -1, slotOf1 = -1, slotOf2 = -1, slotOf3 = -1;
    {
        int nv = 0;
        if ((tn * 4 + 0) % 3 == 2) slotOf0 = nv++;
        if ((tn * 4 + 1) % 3 == 2) slotOf1 = nv++;
        if ((tn * 4 + 2) % 3 == 2) slotOf2 = nv++;
        if ((tn * 4 + 3) % 3 == 2) slotOf3 = nv++;
    }
    uint16_t* vs = &Ab[0][0][0];   // 2 slots x 16384 elems (reuse 64 KB)
    #pragma unroll
    for (int nh = 0; nh < 2; ++nh)
      #pragma unroll
      for (int ni = 0; ni < 2; ++ni) {
        const int cglob = gn + nh * 128 + wn * 32 + ni * 16 + l15;  // flat f col
        const float bias = (cglob < 512) ? q_bias[cglob]
                          : ((cglob < 1024) ? 0.0f : v_bias[cglob - 1024]);
        const int c2 = (wn * 32 + ni * 16) >> 6;
        const int c = nh * 2 + c2;
        const int slot = (c == 0) ? slotOf0 : (c == 1) ? slotOf1
                        : (c == 2) ? slotOf2 : slotOf3;
        const int u = tn * 4 + c;
        const int type = u % 3, h = u / 3;
        if (slot < 0) {   // q or k: direct transposed store + fused sumsq
            uint16_t* T = (type == 0) ? QT : KT;
            const int d = (cglob & 63);
            const int bh = b * 8 + h;
            uint16_t* dst0 = T + ((size_t)bh * 64 + d) * 4096 + (gm & 4095);
            float ss = 0.f;
            #pragma unroll
            for (int mh = 0; mh < 2; ++mh)
              #pragma unroll
              for (int mi = 0; mi < 4; ++mi) {
                union { uint16_t u4[4]; uint64_t q; } pk;
                #pragma unroll
                for (int r = 0; r < 4; ++r) {
                    const float f = acc[mh][mi][nh][ni][r] + bias;
                    pk.u4[r] = f2bf(f);
                    ss += f * f;
                }
                *reinterpret_cast<uint64_t*>(
                    dst0 + mh * 128 + wm * 64 + mi * 16 + lg * 4) = pk.q;
              }
            ss += __shfl_xor(ss, 16, 64);
            ss += __shfl_xor(ss, 32, 64);
            if (lg == 0)
                atomicAdd((type == 0 ? Sq : Sk) + bh * 64 + d, ss);
        } else {          // v: swizzled LDS stage
            const int lcol = (wn & 1) * 32 + ni * 16 + l15;
            #pragma unroll
            for (int mh = 0; mh < 2; ++mh)
              #pragma unroll
              for (int mi = 0; mi < 4; ++mi)
                #pragma unroll
                for (int r = 0; r < 4; ++r) {
                    const int row = mh * 128 + wm * 64 + mi * 16 + lg * 4 + r;
                    vs[slot * 16384 + row * 64 +
                       ((((lcol >> 3) ^ (row & 7)) << 3) | (lcol & 7))] =
                        f2bf(acc[mh][mi][nh][ni][r] + bias);
                }
        }
      }
    __syncthreads();
    // cooperative v write-out (1 or 2 v-chunks per block)
    #pragma unroll
    for (int c = 0; c < 4; ++c) {
        const int slot = (c == 0) ? slotOf0 : (c == 1) ? slotOf1
                        : (c == 2) ? slotOf2 : slotOf3;
        if (slot >= 0) {
            const int hv = (tn * 4 + c) / 3;
            const int row = t >> 1, c0v = (t & 1) * 32;
            uint16_t* dst = VT + (size_t)(gm + row) * 512 + hv * 64 + c0v;
            #pragma unroll
            for (int cc = 0; cc < 4; ++cc) {
                const int col = c0v + cc * 8;
                bf16x8 vv = *reinterpret_cast<const bf16x8*>(
                    &vs[slot * 16384 + row * 64 + (((col >> 3) ^ (row & 7)) << 3)]);
                *reinterpret_cast<bf16x8*>(dst + cc * 8) = vv;
            }
        }
    }
}

// ---------------------------------------------------------------------------
// proj GEMM (8-phase 256^2): out[M][512] = out_t @ Pt^T + proj_b (fp32 out)
// ---------------------------------------------------------------------------
__global__ __launch_bounds__(512, 2) void gemm_proj_kernel(
        const uint16_t* __restrict__ At, const uint16_t* __restrict__ Pt,
        const float* __restrict__ proj_b, float* __restrict__ outp) {
    __shared__ uint16_t Ab[2][2][8192];
    __shared__ uint16_t Bb[2][2][8192];
    const int bx = blockIdx.x;
    const int swz = (bx & 7) * 64 + (bx >> 3);    // nwg=512, bijective
    const int tm = swz >> 1, tn = swz & 1;
    const int gm = tm * 256, gn = tn * 256;
    const int t = threadIdx.x, lane = t & 63, w = t >> 6;
    const int wm = w >> 2, wn = w & 3;
    const int l15 = lane & 15, lg = (lane >> 4) & 3;
    fx4 acc[2][4][2][2] = {};
    const int rowA = t >> 3;
    const int swA = ((t & 7) ^ (rowA & 7)) << 3;
    const uint16_t* gAb = At + (size_t)(gm + rowA) * 512 + swA;
    const uint16_t* gBb = Pt + (size_t)(gn + rowA) * 512 + swA;
    auto stA = [&](int kt_, int half) {
        const int bufi = kt_ & 1; const int kc = (kt_ & 7) * 64;
        gload16(gAb + (size_t)(half * 128) * 512 + kc,      &Ab[bufi][half][t * 8]);
        gload16(gAb + (size_t)(half * 128 + 64) * 512 + kc, &Ab[bufi][half][4096 + t * 8]);
    };
    auto stB = [&](int kt_, int half) {
        const int bufi = kt_ & 1; const int kc = (kt_ & 7) * 64;
        gload16(gBb + (size_t)(half * 128) * 512 + kc,      &Bb[bufi][half][t * 8]);
        gload16(gBb + (size_t)(half * 128 + 64) * 512 + kc, &Bb[bufi][half][4096 + t * 8]);
    };
    stA(0, 0); stB(0, 0); stB(0, 1); stA(0, 1); stA(1, 0); stB(1, 0);
    asm volatile("s_waitcnt vmcnt(8)" ::: "memory");
    __builtin_amdgcn_s_barrier();
    #pragma unroll
    for (int i = 0; i < 4; ++i) {
        const int kt = 2 * i;
        QPHASE(0, 0, 0, stB(kt + 1, 1));
        QPHASE(0, 0, 1, stA(kt + 1, 1));
        QPHASE(0, 1, 0, stA(kt + 2, 0));
        QPHASE(0, 1, 1, stB(kt + 2, 0));
        QPHASE(1, 0, 0, stB(kt + 2, 1));
        QPHASE(1, 0, 1, stA(kt + 2, 1));
        QPHASE(1, 1, 0, stA(kt + 3, 0));
        QPHASE(1, 1, 1, stB(kt + 3, 0));
    }
    asm volatile("s_waitcnt vmcnt(0)" ::: "memory");
    __syncthreads();
    #pragma unroll
    for (int nh = 0; nh < 2; ++nh)
      #pragma unroll
      for (int ni = 0; ni < 2; ++ni) {
        const int col = gn + nh * 128 + wn * 32 + ni * 16 + l15;
        const float bias = proj_b[col];
        #pragma unroll
        for (int mh = 0; mh < 2; ++mh)
          #pragma unroll
          for (int mi = 0; mi < 4; ++mi)
            #pragma unroll
            for (int r = 0; r < 4; ++r) {
                const int row = gm + mh * 128 + wm * 64 + mi * 16 + lg * 4 + r;
                outp[(size_t)row * CDIM + col] = acc[mh][mi][nh][ni][r] + bias;
            }
      }
}

// ---------------------------------------------------------------------------
// attn_qk: Gpart[quarter][bh][d][e] = sum_{n in quarter} q[d,n]*k[e,n]
// double-buffered: stage tile it+1 after barrier, overlapping compute(it).
// ---------------------------------------------------------------------------
__global__ __launch_bounds__(256) void attn_qk_kernel(
        const uint16_t* __restrict__ QT, const uint16_t* __restrict__ KT,
        float* __restrict__ Gpart) {
    __shared__ uint16_t Qs[2][8192];
    __shared__ uint16_t Ks[2][8192];
    const int blk = blockIdx.x;
    const int bh = blk >> 2, quarter = blk & 3;
    const int t = threadIdx.x, lane = t & 63, w = t >> 6;
    const int l15 = lane & 15, lg = lane >> 4;
    const int wr = w >> 1, wc = w & 1;
    fx4 acc[2][2] = {};
    const uint16_t* qbase = QT + (size_t)bh * 64 * 4096;
    const uint16_t* kbase = KT + (size_t)bh * 64 * 4096;
    auto stage = [&](int it_) {
        const int tokt = quarter * 1024 + it_ * 128;
        uint16_t* qd = &Qs[it_ & 1][0];
        uint16_t* kd = &Ks[it_ & 1][0];
        #pragma unroll
        for (int j = 0; j < 4; j++) {
            const int li = j * 256 + t;
            const int row = li >> 4;
            const int src_off = (((li & 15) ^ (row & 7)) << 3);
            gload16(qbase + (size_t)row * 4096 + tokt + src_off, qd + li * 8);
            gload16(kbase + (size_t)row * 4096 + tokt + src_off, kd + li * 8);
        }
    };
    stage(0);
    for (int it = 0; it < 8; it++) {
        asm volatile("s_waitcnt vmcnt(0) lgkmcnt(0)" ::: "memory");
        __builtin_amdgcn_s_barrier();
        if (it < 7) stage(it + 1);
        const uint16_t* Qb = &Qs[it & 1][0];
        const uint16_t* Kb = &Ks[it & 1][0];
        #pragma unroll
        for (int ks = 0; ks < 4; ks++) {
            const int kof = ks * 32 + lg * 8;
            const int ra0 = wr * 32 + l15,      ra1 = wr * 32 + 16 + l15;
            const int rb0 = wc * 32 + l15,      rb1 = wc * 32 + 16 + l15;
            bf16x8 a0 = *reinterpret_cast<const bf16x8*>(&Qb[ra0 * 128 + (kof ^ ((ra0 & 7) << 3))]);
            bf16x8 a1 = *reinterpret_cast<const bf16x8*>(&Qb[ra1 * 128 + (kof ^ ((ra1 & 7) << 3))]);
            bf16x8 b0 = *reinterpret_cast<const bf16x8*>(&Kb[rb0 * 128 + (kof ^ ((rb0 & 7) << 3))]);
            bf16x8 b1 = *reinterpret_cast<const bf16x8*>(&Kb[rb1 * 128 + (kof ^ ((rb1 & 7) << 3))]);
            acc[0][0] = __builtin_amdgcn_mfma_f32_16x16x32_bf16(a0, b0, acc[0][0], 0, 0, 0);
            acc[0][1] = __builtin_amdgcn_mfma_f32_16x16x32_bf16(a0, b1, acc[0][1], 0, 0, 0);
            acc[1][0] = __builtin_amdgcn_mfma_f32_16x16x32_bf16(a1, b0, acc[1][0], 0, 0, 0);
            acc[1][1] = __builtin_amdgcn_mfma_f32_16x16x32_bf16(a1, b1, acc[1][1], 0, 0, 0);
        }
    }
    float* gp = Gpart + (size_t)quarter * 524288 + (size_t)bh * 4096;
    #pragma unroll
    for (int mi = 0; mi < 2; mi++)
        #pragma unroll
        for (int ni = 0; ni < 2; ni++)
            #pragma unroll
            for (int r = 0; r < 4; r++) {
                const int d = wr * 32 + mi * 16 + lg * 4 + r;
                const int e = wc * 32 + ni * 16 + l15;
                gp[d * 64 + e] = acc[mi][ni][r];
            }
}

// ---------------------------------------------------------------------------
// finalize: attnb[bh][d][e] = bf16( softmax_e( exp(scale_h)*G*rq[d]*rk[e] ) )
// ---------------------------------------------------------------------------
__global__ void attn_finalize_kernel(const float* __restrict__ Gpart,
                                     const float* __restrict__ Sq,
                                     const float* __restrict__ Sk,
                                     const float* __restrict__ scale,
                                     uint16_t* __restrict__ attnb) {
    const int bh = blockIdx.x;
    const int h = bh & 7;
    const int t = threadIdx.x;           // 256
    const int e = t & 63, w = t >> 6;
    const float es = expf(scale[h]);
    const float rk = rsqrtf(fmaxf(Sk[bh * 64 + e], 1.55e-5f));
    const float* g0 = Gpart + (size_t)bh * 4096;
    for (int d = w; d < 64; d += 4) {
        const float rq = rsqrtf(fmaxf(Sq[bh * 64 + d], 1.55e-5f));
        float g = g0[d * 64 + e] + g0[524288 + d * 64 + e]
                + g0[1048576 + d * 64 + e] + g0[1572864 + d * 64 + e];
        float x = es * g * rq * rk;
        float m = x;
        #pragma unroll
        for (int off = 32; off; off >>= 1) m = fmaxf(m, __shfl_xor(m, off, 64));
        float p = expf(x - m);
        float s = p;
        #pragma unroll
        for (int off = 32; off; off >>= 1) s += __shfl_xor(s, off, 64);
        attnb[(size_t)bh * 4096 + d * 64 + e] = f2bf(p / s);
    }
}

// ---------------------------------------------------------------------------
// pv (MFMA): out_t[n][h*64+d] = sum_e attnb[bh][d][e] * v[n][e]
// ---------------------------------------------------------------------------
__global__ __launch_bounds__(256) void pv_kernel(
        const uint16_t* __restrict__ VT, const uint16_t* __restrict__ attnb,
        uint16_t* __restrict__ out_t) {
    __shared__ uint16_t Vs[64 * 64];   // 8 KB
    __shared__ uint16_t Os[64 * 64];   // 8 KB
    const int blk = blockIdx.x;
    const int bh = blk >> 6, chunk = blk & 63;
    const int b = bh >> 3, h = bh & 7;
    const int n0 = chunk * 64;
    const int t = threadIdx.x, lane = t & 63, w = t >> 6;
    const int l15 = lane & 15, lg = lane >> 4;
    #pragma unroll
    for (int j = 0; j < 2; j++) {
        const int li = j * 256 + t;
        const int row = li >> 3;
        const int src_off = (((li & 7) ^ (row & 7)) << 3);
        gload16(VT + (size_t)(b * NTOK + n0 + row) * 512 + h * 64 + src_off, &Vs[li * 8]);
    }
    bf16x8 bfr[4][2];
    const uint16_t* ab = attnb + (size_t)bh * 4096;
    #pragma unroll
    for (int n = 0; n < 4; n++)
        #pragma unroll
        for (int ks = 0; ks < 2; ks++)
            bfr[n][ks] = *reinterpret_cast<const bf16x8*>(ab + (n * 16 + l15) * 64 + ks * 32 + lg * 8);
    __syncthreads();
    fx4 acc[4] = {};
    #pragma unroll
    for (int ks = 0; ks < 2; ks++) {
        const int row = w * 16 + l15;
        const int kof = ks * 32 + lg * 8;
        bf16x8 a = *reinterpret_cast<const bf16x8*>(&Vs[row * 64 + (kof ^ ((row & 7) << 3))]);
        #pragma unroll
        for (int n = 0; n < 4; n++)
            acc[n] = __builtin_amdgcn_mfma_f32_16x16x32_bf16(a, bfr[n][ks], acc[n], 0, 0, 0);
    }
    #pragma unroll
    for (int n = 0; n < 4; n++)
        #pragma unroll
        for (int r = 0; r < 4; r++) {
            const int row = w * 16 + lg * 4 + r;
            const int col = n * 16 + l15;
            Os[row * 64 + (col ^ ((row & 7) << 3))] = f2bf(acc[n][r]);
        }
    __syncthreads();
    {
        const int tr = t >> 2, c0 = (t & 3) * 16;
        uint16_t* orow = out_t + (size_t)(b * NTOK + n0 + tr) * CDIM + h * 64;
        #pragma unroll
        for (int cc2 = 0; cc2 < 2; cc2++) {
            const int c = c0 + cc2 * 8;
            const int chnk = (c >> 3) ^ (tr & 7);
            bf16x8 vv = *reinterpret_cast<const bf16x8*>(&Os[tr * 64 + (chnk << 3)]);
            *reinterpret_cast<bf16x8*>(orow + c) = vv;
        }
    }
}

// ---------------------------------------------------------------------------
// ws layout (bytes):
//   0          Wt      1572864
//   1572864    Pt       524288
//   2097152    Sq        32768
//   2129920    Sk        32768
//   2162688    Gpart   8388608
//   10551296   attnb   1048576
//   11599872   QT     67108864   [bh][d][tok]
//   78708736   KT     67108864
//   145817600  VT     67108864   [token][c]
//   212926464  Xb/out_t 67108864 (disjoint-lifetime alias)
//   total 280035328 (~267 MB)
// ---------------------------------------------------------------------------
extern "C" void kernel_launch(void* const* d_in, const int* in_sizes, int n_in,
                              void* d_out, int out_size, void* d_ws, size_t ws_size,
                              hipStream_t stream) {
    (void)in_sizes; (void)n_in; (void)out_size; (void)ws_size;
    const float* x      = (const float*)d_in[0];
    const float* qkv_w  = (const float*)d_in[1];
    const float* q_bias = (const float*)d_in[2];
    const float* v_bias = (const float*)d_in[3];
    const float* scale  = (const float*)d_in[4];
    const float* proj_w = (const float*)d_in[5];
    const float* proj_b = (const float*)d_in[6];
    float* out = (float*)d_out;

    char* wsp = (char*)d_ws;
    uint16_t* Wt    = (uint16_t*)(wsp);
    uint16_t* Pt    = (uint16_t*)(wsp + 1572864);
    float*    Sq    = (float*)   (wsp + 2097152);
    float*    Sk    = (float*)   (wsp + 2129920);
    float*    Gpart = (float*)   (wsp + 2162688);
    uint16_t* attnb = (uint16_t*)(wsp + 10551296);
    uint16_t* QT    = (uint16_t*)(wsp + 11599872);
    uint16_t* KT    = (uint16_t*)(wsp + 78708736);
    uint16_t* VT    = (uint16_t*)(wsp + 145817600);
    uint16_t* Xb    = (uint16_t*)(wsp + 212926464);
    uint16_t* out_t = Xb;   // disjoint lifetime alias

    hipLaunchKernelGGL(transpose_w_kernel, dim3(1024), dim3(256), 0, stream,
                       qkv_w, proj_w, Wt, Pt);
    hipLaunchKernelGGL(prep_kernel, dim3(2048), dim3(256), 0, stream,
                       x, Xb, Sq);
    hipLaunchKernelGGL(gemm_qkv_kernel, dim3(1536), dim3(512), 0, stream,
                       Xb, Wt, q_bias, v_bias, QT, KT, VT, Sq, Sk);
    hipLaunchKernelGGL(attn_qk_kernel, dim3(512), dim3(256), 0, stream,
                       QT, KT, Gpart);
    hipLaunchKernelGGL(attn_finalize_kernel, dim3(128), dim3(256), 0, stream,
                       Gpart, Sq, Sk, scale, attnb);
    hipLaunchKernelGGL(pv_kernel, dim3(8192), dim3(256), 0, stream,
                       VT, attnb, out_t);
    hipLaunchKernelGGL(gemm_proj_kernel, dim3(512), dim3(512), 0, stream,
                       out_t, Pt, proj_b, out);
}